// Round 1
// baseline (210.999 us; speedup 1.0000x reference)
//
#include <hip/hip_runtime.h>

#define BATCH  4096
#define NROWS  8192
#define LATENT 2048
#define ZDIM   128
#define PRIORc       0.3f
#define PRIOR_PRIMEc 0.5f

typedef __attribute__((ext_vector_type(8))) short bf16x8;  // 8 bf16 = 4 VGPRs
typedef __attribute__((ext_vector_type(4))) float f32x4;   // MFMA C/D

__device__ inline unsigned short f2bf_rne(float f) {
    unsigned int u = __float_as_uint(f);
    u = u + 0x7fffu + ((u >> 16) & 1u);
    return (unsigned short)(u >> 16);
}

__device__ inline float wave_reduce_sum(float v) {
#pragma unroll
    for (int m = 1; m < 64; m <<= 1) v += __shfl_xor(v, m, 64);
    return v;
}

// ---------------------------------------------------------------------------
// zn = z / max(||z||, eps), scaled by sqrt(1/TEMP)=sqrt(2) (so dot = sim/TEMP),
// cast to bf16 and stored in MFMA-fragment-swizzled layout:
//   chunk index (g*4 + kt), lane = q*16 + (row&15) holds k = kt*32 + q*8 .. +7
// so a fragment load is znb_frag[(g*4+kt)*64 + lane] : 16B/lane, coalesced.
// ---------------------------------------------------------------------------
__global__ void k_znorm(const float* __restrict__ z_i, const float* __restrict__ z_j,
                        unsigned short* __restrict__ znb, float* __restrict__ inv_norm) {
    int wave = threadIdx.x >> 6, lane = threadIdx.x & 63;
    int r = blockIdx.x * 4 + wave;                       // 2048 blocks x 4 waves
    const float* zr = (r < BATCH) ? (z_i + (size_t)r * ZDIM)
                                  : (z_j + (size_t)(r - BATCH) * ZDIM);
    float2 v = ((const float2*)zr)[lane];                // k = 2*lane, 2*lane+1
    float ss = v.x * v.x + v.y * v.y;
    ss = wave_reduce_sum(ss);
    float inv = 1.0f / fmaxf(sqrtf(ss), 1e-8f);
    if (lane == 0) inv_norm[r] = inv;
    float scale = inv * 1.41421356237f;                  // fold 1/sqrt(TEMP)
    int g = r >> 4, rr = r & 15;
    int kt = lane >> 4;
    int q  = (lane >> 2) & 3;
    int j  = (lane & 3) * 2;
    size_t off = ((size_t)(g * 4 + kt) * 64 + (q * 16 + rr)) * 8 + j;
    ushort2 w2; w2.x = f2bf_rne(v.x * scale); w2.y = f2bf_rne(v.y * scale);
    *(ushort2*)(znb + off) = w2;
}

// logits[r] = dot(h_row, W) + b   (one wave per row, float4, shuffle reduce)
__global__ void k_logits(const float* __restrict__ h_i, const float* __restrict__ h_j,
                         const float* __restrict__ W, const float* __restrict__ b,
                         float* __restrict__ logits) {
    int wave = threadIdx.x >> 6, lane = threadIdx.x & 63;
    int r = blockIdx.x * 4 + wave;
    const float* h = (r < BATCH) ? (h_i + (size_t)r * LATENT)
                                 : (h_j + (size_t)(r - BATCH) * LATENT);
    const float4* h4 = (const float4*)h;
    const float4* w4 = (const float4*)W;
    float s = 0.f;
#pragma unroll
    for (int it = 0; it < 8; ++it) {
        float4 a = h4[it * 64 + lane];
        float4 w = w4[it * 64 + lane];
        s += a.x * w.x + a.y * w.y + a.z * w.z + a.w * w.w;
    }
    s = wave_reduce_sum(s);
    if (lane == 0) logits[r] = s + b[0];
}

// nnPU risk from both logit sets; single block.
__global__ void k_onnpu(const float* __restrict__ logits, const int* __restrict__ target,
                        float* __restrict__ out_onnpu) {
    float cp = 0, cu = 0, a_pn = 0, a_pp = 0, a_u = 0, b_pn = 0, b_pp = 0, b_u = 0;
    for (int r = threadIdx.x; r < BATCH; r += 256) {
        float li = logits[r], lj = logits[BATCH + r];
        int t = target[r];
        float si_n = 1.f / (1.f + __expf(li));    // sigmoid(-li)
        float si_p = 1.f / (1.f + __expf(-li));   // sigmoid(li)
        float sj_n = 1.f / (1.f + __expf(lj));
        float sj_p = 1.f / (1.f + __expf(-lj));
        if (t == 1) { cp += 1.f; a_pn += si_n; a_pp += si_p; b_pn += sj_n; b_pp += sj_p; }
        else        { cu += 1.f; a_u += si_p; b_u += sj_p; }
    }
    __shared__ float red[4][8];
    float vals[8] = {cp, cu, a_pn, a_pp, a_u, b_pn, b_pp, b_u};
    int wave = threadIdx.x >> 6, lane = threadIdx.x & 63;
#pragma unroll
    for (int i = 0; i < 8; ++i) vals[i] = wave_reduce_sum(vals[i]);
    if (lane == 0) {
#pragma unroll
        for (int i = 0; i < 8; ++i) red[wave][i] = vals[i];
    }
    __syncthreads();
    if (threadIdx.x == 0) {
        float v[8];
#pragma unroll
        for (int i = 0; i < 8; ++i) v[i] = red[0][i] + red[1][i] + red[2][i] + red[3][i];
        float np = fmaxf(1.f, v[0]), nu = fmaxf(1.f, v[1]);
        float pr_i = PRIOR_PRIMEc / np * v[2];
        float nr_i = (1.f - PRIOR_PRIMEc) / (nu * (1.f - PRIORc)) * v[4]
                   - (1.f - PRIOR_PRIMEc) * PRIORc / (np * (1.f - PRIORc)) * v[3];
        float li_loss = (nr_i < 0.f) ? -nr_i : (pr_i + nr_i);
        float pr_j = PRIOR_PRIMEc / np * v[5];
        float nr_j = (1.f - PRIOR_PRIMEc) / (nu * (1.f - PRIORc)) * v[7]
                   - (1.f - PRIOR_PRIMEc) * PRIORc / (np * (1.f - PRIORc)) * v[6];
        float lj_loss = (nr_j < 0.f) ? -nr_j : (pr_j + nr_j);
        *out_onnpu = 0.5f * (li_loss + lj_loss);
    }
}

// Main: S_row[r] += sum_{c in block cols, c != r} exp(sim[r][c])
// per wave: 64x64 output tile = 4x4 grid of 16x16x32 MFMAs, K=128 in regs.
__global__ void __launch_bounds__(256) k_sim(const unsigned short* __restrict__ znb,
                                             float* __restrict__ S_row) {
    int lane = threadIdx.x & 63, wave = threadIdx.x >> 6;
    int row0 = blockIdx.y * 128 + (wave >> 1) * 64;
    int col0 = blockIdx.x * 128 + (wave & 1) * 64;
    int q = lane >> 4, t = lane & 15;
    const bf16x8* zf = (const bf16x8*)znb;
    int gA = row0 >> 4, gB = col0 >> 4;   // 16-row group indices
    f32x4 acc[4][4];
    f32x4 zero = {0.f, 0.f, 0.f, 0.f};
#pragma unroll
    for (int mt = 0; mt < 4; ++mt)
#pragma unroll
        for (int nt = 0; nt < 4; ++nt) acc[mt][nt] = zero;
#pragma unroll
    for (int kt = 0; kt < 4; ++kt) {
        bf16x8 a[4], b[4];
#pragma unroll
        for (int mt = 0; mt < 4; ++mt) a[mt] = zf[(size_t)((gA + mt) * 4 + kt) * 64 + lane];
#pragma unroll
        for (int nt = 0; nt < 4; ++nt) b[nt] = zf[(size_t)((gB + nt) * 4 + kt) * 64 + lane];
#pragma unroll
        for (int mt = 0; mt < 4; ++mt)
#pragma unroll
            for (int nt = 0; nt < 4; ++nt)
                acc[mt][nt] = __builtin_amdgcn_mfma_f32_16x16x32_bf16(a[mt], b[nt], acc[mt][nt], 0, 0, 0);
    }
    // epilogue: exp, mask diagonal, reduce cols (lanes t=0..15), atomic per row
#pragma unroll
    for (int mt = 0; mt < 4; ++mt) {
#pragma unroll
        for (int reg = 0; reg < 4; ++reg) {
            int grow = row0 + mt * 16 + q * 4 + reg;   // C/D: row=(lane>>4)*4+reg
            float s = 0.f;
#pragma unroll
            for (int nt = 0; nt < 4; ++nt) {
                int gcol = col0 + nt * 16 + t;         // C/D: col=lane&15
                float e = __expf(acc[mt][nt][reg]);
                s += (grow == gcol) ? 0.f : e;
            }
            s += __shfl_xor(s, 1, 64);
            s += __shfl_xor(s, 2, 64);
            s += __shfl_xor(s, 4, 64);
            s += __shfl_xor(s, 8, 64);
            if (t == 0) atomicAdd(&S_row[grow], s);
        }
    }
}

// exact fp32 positive-pair logit: pos[r] = dot(z_r, z_p) * inv_r * inv_p / TEMP
__global__ void k_pos(const float* __restrict__ z_i, const float* __restrict__ z_j,
                      const float* __restrict__ inv_norm, float* __restrict__ pos) {
    int wave = threadIdx.x >> 6, lane = threadIdx.x & 63;
    int r = blockIdx.x * 4 + wave;
    int p = (r + BATCH) & (NROWS - 1);
    const float* zr = (r < BATCH) ? (z_i + (size_t)r * ZDIM)
                                  : (z_j + (size_t)(r - BATCH) * ZDIM);
    const float* zp = (p < BATCH) ? (z_i + (size_t)p * ZDIM)
                                  : (z_j + (size_t)(p - BATCH) * ZDIM);
    float2 a = ((const float2*)zr)[lane];
    float2 c = ((const float2*)zp)[lane];
    float d = a.x * c.x + a.y * c.y;
    d = wave_reduce_sum(d);
    if (lane == 0) pos[r] = 2.0f * d * inv_norm[r] * inv_norm[p];
}

__global__ void k_final(const float* __restrict__ S_row, const float* __restrict__ pos,
                        const float* __restrict__ onnpu, const float* __restrict__ w_onnpu,
                        float* __restrict__ out) {
    float s = 0.f;
    for (int r = threadIdx.x; r < NROWS; r += 1024)
        s += logf(S_row[r]) - pos[r];
    __shared__ float red[16];
    int wave = threadIdx.x >> 6, lane = threadIdx.x & 63;
    s = wave_reduce_sum(s);
    if (lane == 0) red[wave] = s;
    __syncthreads();
    if (threadIdx.x == 0) {
        float tot = 0.f;
#pragma unroll
        for (int i = 0; i < 16; ++i) tot += red[i];
        float ntxent = tot / (float)NROWS;
        float w = w_onnpu[0];
        out[0] = w * onnpu[0] + (1.f - w) * ntxent;
    }
}

extern "C" void kernel_launch(void* const* d_in, const int* in_sizes, int n_in,
                              void* d_out, int out_size, void* d_ws, size_t ws_size,
                              hipStream_t stream) {
    const float* h_i = (const float*)d_in[0];
    const float* h_j = (const float*)d_in[1];
    const float* z_i = (const float*)d_in[2];
    const float* z_j = (const float*)d_in[3];
    const int* target = (const int*)d_in[4];
    const float* W = (const float*)d_in[5];
    const float* b = (const float*)d_in[6];
    const float* w_onnpu = (const float*)d_in[7];

    char* ws = (char*)d_ws;
    unsigned short* znb = (unsigned short*)ws;                  // 2 MB swizzled bf16
    float* inv_norm = (float*)(ws + 2097152);                   // 32 KB
    float* logits   = (float*)(ws + 2097152 + 32768);           // 32 KB
    float* S_row    = (float*)(ws + 2097152 + 65536);           // 32 KB
    float* pos      = (float*)(ws + 2097152 + 98304);           // 32 KB
    float* onnpu    = (float*)(ws + 2097152 + 131072);          // 4 B
    float* out = (float*)d_out;

    hipMemsetAsync(S_row, 0, NROWS * sizeof(float), stream);
    k_znorm<<<2048, 256, 0, stream>>>(z_i, z_j, znb, inv_norm);
    k_logits<<<2048, 256, 0, stream>>>(h_i, h_j, W, b, logits);
    k_onnpu<<<1, 256, 0, stream>>>(logits, target, onnpu);
    dim3 g(64, 64);
    k_sim<<<g, 256, 0, stream>>>(znb, S_row);
    k_pos<<<2048, 256, 0, stream>>>(z_i, z_j, inv_norm, pos);
    k_final<<<1, 1024, 0, stream>>>(S_row, pos, onnpu, w_onnpu, out);
}

// Round 2
// 148.960 us; speedup vs baseline: 1.4165x; 1.4165x over previous
//
#include <hip/hip_runtime.h>

#define BATCH  4096
#define NROWS  8192
#define LATENT 2048
#define ZDIM   128
#define PRIORc       0.3f
#define PRIOR_PRIMEc 0.5f

typedef __attribute__((ext_vector_type(8))) short bf16x8;  // 8 bf16 = 4 VGPRs
typedef __attribute__((ext_vector_type(4))) float f32x4;   // MFMA C/D

__device__ inline unsigned short f2bf_rne(float f) {
    unsigned int u = __float_as_uint(f);
    u = u + 0x7fffu + ((u >> 16) & 1u);
    return (unsigned short)(u >> 16);
}

__device__ inline float wave_reduce_sum(float v) {
#pragma unroll
    for (int m = 1; m < 64; m <<= 1) v += __shfl_xor(v, m, 64);
    return v;
}

// ---------------------------------------------------------------------------
// zn = z / max(||z||, eps), scaled by sqrt(1/TEMP)=sqrt(2) (so dot = sim/TEMP),
// cast to bf16, stored MFMA-fragment-swizzled:
//   chunk (g*4 + kt), lane = q*16 + (row&15) holds k = kt*32 + q*8 .. +7
// fragment load = zf[(g*4+kt)*64 + lane] : 16B/lane fully coalesced.
// ---------------------------------------------------------------------------
__global__ void k_znorm(const float* __restrict__ z_i, const float* __restrict__ z_j,
                        unsigned short* __restrict__ znb) {
    int wave = threadIdx.x >> 6, lane = threadIdx.x & 63;
    int r = blockIdx.x * 4 + wave;
    const float* zr = (r < BATCH) ? (z_i + (size_t)r * ZDIM)
                                  : (z_j + (size_t)(r - BATCH) * ZDIM);
    float2 v = ((const float2*)zr)[lane];
    float ss = v.x * v.x + v.y * v.y;
    ss = wave_reduce_sum(ss);
    float scale = (1.0f / fmaxf(sqrtf(ss), 1e-8f)) * 1.41421356237f;
    int g = r >> 4, rr = r & 15;
    int kt = lane >> 4;
    int q  = (lane >> 2) & 3;
    int j  = (lane & 3) * 2;
    size_t off = ((size_t)(g * 4 + kt) * 64 + (q * 16 + rr)) * 8 + j;
    ushort2 w2; w2.x = f2bf_rne(v.x * scale); w2.y = f2bf_rne(v.y * scale);
    *(ushort2*)(znb + off) = w2;
}

// logits[r] = dot(h_row, W) + b   (one wave per row, float4, shuffle reduce)
__global__ void k_logits(const float* __restrict__ h_i, const float* __restrict__ h_j,
                         const float* __restrict__ W, const float* __restrict__ b,
                         float* __restrict__ logits) {
    int wave = threadIdx.x >> 6, lane = threadIdx.x & 63;
    int r = blockIdx.x * 4 + wave;
    const float* h = (r < BATCH) ? (h_i + (size_t)r * LATENT)
                                 : (h_j + (size_t)(r - BATCH) * LATENT);
    const float4* h4 = (const float4*)h;
    const float4* w4 = (const float4*)W;
    float s = 0.f;
#pragma unroll
    for (int it = 0; it < 8; ++it) {
        float4 a = h4[it * 64 + lane];
        float4 w = w4[it * 64 + lane];
        s += a.x * w.x + a.y * w.y + a.z * w.z + a.w * w.w;
    }
    s = wave_reduce_sum(s);
    if (lane == 0) logits[r] = s + b[0];
}

// nnPU partial sums: 16 blocks x 256, one row per thread, atomic into acc8.
// acc8: {n_pos, n_unl, i_pn, i_pp, i_u, j_pn, j_pp, j_u}
__global__ void k_onnpu_part(const float* __restrict__ logits, const int* __restrict__ target,
                             float* __restrict__ acc8) {
    int r = blockIdx.x * 256 + threadIdx.x;
    float li = logits[r], lj = logits[BATCH + r];
    int t = target[r];
    bool pos = (t == 1);
    float v[8];
    v[0] = pos ? 1.f : 0.f;
    v[1] = pos ? 0.f : 1.f;
    v[2] = pos ? 1.f / (1.f + __expf(li)) : 0.f;    // sigmoid(-li)
    v[3] = pos ? 1.f / (1.f + __expf(-li)) : 0.f;   // sigmoid(li)
    v[4] = pos ? 0.f : 1.f / (1.f + __expf(-li));
    v[5] = pos ? 1.f / (1.f + __expf(lj)) : 0.f;
    v[6] = pos ? 1.f / (1.f + __expf(-lj)) : 0.f;
    v[7] = pos ? 0.f : 1.f / (1.f + __expf(-lj));
    int lane = threadIdx.x & 63;
#pragma unroll
    for (int i = 0; i < 8; ++i) {
        float s = wave_reduce_sum(v[i]);
        if (lane == 0) atomicAdd(&acc8[i], s);
    }
}

// ---------------------------------------------------------------------------
// Flash-style sim+exp+rowsum: block = 128-row stripe x 512-col group.
// A fragments resident in registers; nt-outer acc reuse; per-lane row-sum
// accumulation; single shuffle+atomic epilogue per wave.
// ---------------------------------------------------------------------------
__global__ void __launch_bounds__(256, 3) k_sim(const unsigned short* __restrict__ znb,
                                                float* __restrict__ S_row) {
    int lane = threadIdx.x & 63, wave = threadIdx.x >> 6;
    int q = lane >> 4, t = lane & 15;
    int row0 = blockIdx.x * 128 + (wave >> 1) * 64;
    int gA = row0 >> 4;
    const bf16x8* zf = (const bf16x8*)znb;

    bf16x8 a[4][4];
#pragma unroll
    for (int mt = 0; mt < 4; ++mt)
#pragma unroll
        for (int kt = 0; kt < 4; ++kt)
            a[mt][kt] = zf[(size_t)((gA + mt) * 4 + kt) * 64 + lane];

    float s[16];
#pragma unroll
    for (int i = 0; i < 16; ++i) s[i] = 0.f;

    int colbase = blockIdx.y * 512 + (wave & 1) * 64;
#pragma unroll 1
    for (int it = 0; it < 4; ++it) {
        int col0 = colbase + it * 128;
        int gB = col0 >> 4;
#pragma unroll
        for (int nt = 0; nt < 4; ++nt) {
            bf16x8 b[4];
#pragma unroll
            for (int kt = 0; kt < 4; ++kt)
                b[kt] = zf[(size_t)((gB + nt) * 4 + kt) * 64 + lane];
            f32x4 acc[4];
            f32x4 zero = {0.f, 0.f, 0.f, 0.f};
#pragma unroll
            for (int mt = 0; mt < 4; ++mt) acc[mt] = zero;
#pragma unroll
            for (int kt = 0; kt < 4; ++kt)
#pragma unroll
                for (int mt = 0; mt < 4; ++mt)
                    acc[mt] = __builtin_amdgcn_mfma_f32_16x16x32_bf16(a[mt][kt], b[kt], acc[mt], 0, 0, 0);
            int gcol = col0 + nt * 16 + t;
#pragma unroll
            for (int mt = 0; mt < 4; ++mt) {
                int rowb = row0 + mt * 16 + q * 4;
#pragma unroll
                for (int reg = 0; reg < 4; ++reg) {
                    float e = __expf(acc[mt][reg]);
                    s[mt * 4 + reg] += (rowb + reg == gcol) ? 0.f : e;
                }
            }
        }
    }
    // once per wave: reduce across the 16 t-lanes, one atomic per row
#pragma unroll
    for (int i = 0; i < 16; ++i) {
        float v = s[i];
        v += __shfl_xor(v, 1, 64);
        v += __shfl_xor(v, 2, 64);
        v += __shfl_xor(v, 4, 64);
        v += __shfl_xor(v, 8, 64);
        if (t == 0) atomicAdd(&S_row[row0 + (i >> 2) * 16 + q * 4 + (i & 3)], v);
    }
}

// exact fp32 positive-pair logit, self-contained (computes both norms)
__global__ void k_pos(const float* __restrict__ z_i, const float* __restrict__ z_j,
                      float* __restrict__ pos) {
    int wave = threadIdx.x >> 6, lane = threadIdx.x & 63;
    int r = blockIdx.x * 4 + wave;
    int p = (r + BATCH) & (NROWS - 1);
    const float* zr = (r < BATCH) ? (z_i + (size_t)r * ZDIM)
                                  : (z_j + (size_t)(r - BATCH) * ZDIM);
    const float* zp = (p < BATCH) ? (z_i + (size_t)p * ZDIM)
                                  : (z_j + (size_t)(p - BATCH) * ZDIM);
    float2 a = ((const float2*)zr)[lane];
    float2 c = ((const float2*)zp)[lane];
    float d = a.x * c.x + a.y * c.y;
    float sr = a.x * a.x + a.y * a.y;
    float sp = c.x * c.x + c.y * c.y;
    d = wave_reduce_sum(d);
    sr = wave_reduce_sum(sr);
    sp = wave_reduce_sum(sp);
    if (lane == 0)
        pos[r] = 2.0f * d / (fmaxf(sqrtf(sr), 1e-8f) * fmaxf(sqrtf(sp), 1e-8f));
}

__global__ void k_final(const float* __restrict__ S_row, const float* __restrict__ pos,
                        const float* __restrict__ acc8, const float* __restrict__ w_onnpu,
                        float* __restrict__ out) {
    float s = 0.f;
    for (int r = threadIdx.x; r < NROWS; r += 1024)
        s += __logf(S_row[r]) - pos[r];
    __shared__ float red[16];
    int wave = threadIdx.x >> 6, lane = threadIdx.x & 63;
    s = wave_reduce_sum(s);
    if (lane == 0) red[wave] = s;
    __syncthreads();
    if (threadIdx.x == 0) {
        float tot = 0.f;
#pragma unroll
        for (int i = 0; i < 16; ++i) tot += red[i];
        float ntxent = tot / (float)NROWS;
        float np = fmaxf(1.f, acc8[0]), nu = fmaxf(1.f, acc8[1]);
        float pr_i = PRIOR_PRIMEc / np * acc8[2];
        float nr_i = (1.f - PRIOR_PRIMEc) / (nu * (1.f - PRIORc)) * acc8[4]
                   - (1.f - PRIOR_PRIMEc) * PRIORc / (np * (1.f - PRIORc)) * acc8[3];
        float li_loss = (nr_i < 0.f) ? -nr_i : (pr_i + nr_i);
        float pr_j = PRIOR_PRIMEc / np * acc8[5];
        float nr_j = (1.f - PRIOR_PRIMEc) / (nu * (1.f - PRIORc)) * acc8[7]
                   - (1.f - PRIOR_PRIMEc) * PRIORc / (np * (1.f - PRIORc)) * acc8[6];
        float lj_loss = (nr_j < 0.f) ? -nr_j : (pr_j + nr_j);
        float onnpu = 0.5f * (li_loss + lj_loss);
        float w = w_onnpu[0];
        out[0] = w * onnpu + (1.f - w) * ntxent;
    }
}

extern "C" void kernel_launch(void* const* d_in, const int* in_sizes, int n_in,
                              void* d_out, int out_size, void* d_ws, size_t ws_size,
                              hipStream_t stream) {
    const float* h_i = (const float*)d_in[0];
    const float* h_j = (const float*)d_in[1];
    const float* z_i = (const float*)d_in[2];
    const float* z_j = (const float*)d_in[3];
    const int* target = (const int*)d_in[4];
    const float* W = (const float*)d_in[5];
    const float* b = (const float*)d_in[6];
    const float* w_onnpu = (const float*)d_in[7];

    char* ws = (char*)d_ws;
    unsigned short* znb = (unsigned short*)ws;              // 2 MB swizzled bf16
    float* logits = (float*)(ws + 2097152);                 // 32 KB
    float* S_row  = (float*)(ws + 2097152 + 32768);         // 32 KB
    float* acc8   = (float*)(ws + 2097152 + 65536);         // 256 B
    float* pos    = (float*)(ws + 2097152 + 65536 + 256);   // 32 KB
    float* out = (float*)d_out;

    hipMemsetAsync(S_row, 0, 32768 + 256, stream);          // S_row + acc8
    k_znorm<<<2048, 256, 0, stream>>>(z_i, z_j, znb);
    k_logits<<<2048, 256, 0, stream>>>(h_i, h_j, W, b, logits);
    k_onnpu_part<<<16, 256, 0, stream>>>(logits, target, acc8);
    dim3 g(64, 16);
    k_sim<<<g, 256, 0, stream>>>(znb, S_row);
    k_pos<<<2048, 256, 0, stream>>>(z_i, z_j, pos);
    k_final<<<1, 1024, 0, stream>>>(S_row, pos, acc8, w_onnpu, out);
}

// Round 3
// 136.187 us; speedup vs baseline: 1.5493x; 1.0938x over previous
//
#include <hip/hip_runtime.h>

#define BATCH  4096
#define NROWS  8192
#define LATENT 2048
#define ZDIM   128
#define PRIORc       0.3f
#define PRIOR_PRIMEc 0.5f

typedef __attribute__((ext_vector_type(8))) short bf16x8;  // 8 bf16 = 4 VGPRs
typedef __attribute__((ext_vector_type(4))) float f32x4;   // MFMA C/D

__device__ inline unsigned short f2bf_rne(float f) {
    unsigned int u = __float_as_uint(f);
    u = u + 0x7fffu + ((u >> 16) & 1u);
    return (unsigned short)(u >> 16);
}

__device__ inline float wave_reduce_sum(float v) {
#pragma unroll
    for (int m = 1; m < 64; m <<= 1) v += __shfl_xor(v, m, 64);
    return v;
}

// ---------------------------------------------------------------------------
// One wave per positive pair (r, r+BATCH): normalize both rows, scale by
// sqrt(2) (folds 1/TEMP into the dot), cast bf16, store MFMA-fragment-
// swizzled; also the exact fp32 positive-pair logit for both rows.
// Swizzle: chunk (g*4+kt), lane q*16+(row&15) holds k = kt*32+q*8 .. +7
// so a fragment load is zf[(g*4+kt)*64+lane]: 16B/lane fully coalesced.
// ---------------------------------------------------------------------------
__global__ void k_zprep(const float* __restrict__ z_i, const float* __restrict__ z_j,
                        unsigned short* __restrict__ znb, float* __restrict__ pos) {
    int wave = threadIdx.x >> 6, lane = threadIdx.x & 63;
    int r = blockIdx.x * 4 + wave;            // 0..4095
    int p = r + BATCH;
    float2 a = ((const float2*)(z_i + (size_t)r * ZDIM))[lane];
    float2 c = ((const float2*)(z_j + (size_t)r * ZDIM))[lane];
    float sa = a.x * a.x + a.y * a.y;
    float sc = c.x * c.x + c.y * c.y;
    float dd = a.x * c.x + a.y * c.y;
    sa = wave_reduce_sum(sa);
    sc = wave_reduce_sum(sc);
    dd = wave_reduce_sum(dd);
    float inva = 1.f / fmaxf(sqrtf(sa), 1e-8f);
    float invc = 1.f / fmaxf(sqrtf(sc), 1e-8f);
    if (lane == 0) {
        float pv = 2.0f * dd * inva * invc;   // cos-sim / TEMP, exact fp32
        pos[r] = pv;
        pos[p] = pv;
    }
    int kt = lane >> 4;
    int q  = (lane >> 2) & 3;
    int j  = (lane & 3) * 2;
    int lrow = q * 16;
    float fa = inva * 1.41421356237f, fc = invc * 1.41421356237f;
    {   // row r (from z_i)
        size_t off = ((size_t)((r >> 4) * 4 + kt) * 64 + (lrow + (r & 15))) * 8 + j;
        ushort2 w2; w2.x = f2bf_rne(a.x * fa); w2.y = f2bf_rne(a.y * fa);
        *(ushort2*)(znb + off) = w2;
    }
    {   // row p (from z_j)
        size_t off = ((size_t)((p >> 4) * 4 + kt) * 64 + (lrow + (p & 15))) * 8 + j;
        ushort2 w2; w2.x = f2bf_rne(c.x * fc); w2.y = f2bf_rne(c.y * fc);
        *(ushort2*)(znb + off) = w2;
    }
}

// ---------------------------------------------------------------------------
// Mega kernel: blocks [0,1024) = sim (compute-bound), [1024,3072) = logits
// (HBM-bound). Opposite rooflines co-scheduled across CUs.
// sim: 128-row stripe x 512-col group per block; A frags register-resident;
// B frags software-pipelined (prefetch next nt during MFMA+exp of current);
// per-lane row-sum accumulators; one shuffle+atomic epilogue per wave.
// ---------------------------------------------------------------------------
__global__ void __launch_bounds__(256, 3) k_mega(
        const unsigned short* __restrict__ znb, float* __restrict__ S_row,
        const float* __restrict__ h_i, const float* __restrict__ h_j,
        const float* __restrict__ W, const float* __restrict__ bb,
        float* __restrict__ logits) {
    int bid = blockIdx.x;
    int lane = threadIdx.x & 63, wave = threadIdx.x >> 6;
    if (bid < 1024) {
        int q = lane >> 4, t = lane & 15;
        int row0 = (bid & 63) * 128 + (wave >> 1) * 64;
        int gA = row0 >> 4;
        const bf16x8* zf = (const bf16x8*)znb;

        bf16x8 a[4][4];
#pragma unroll
        for (int mt = 0; mt < 4; ++mt)
#pragma unroll
            for (int kt = 0; kt < 4; ++kt)
                a[mt][kt] = zf[(size_t)((gA + mt) * 4 + kt) * 64 + lane];

        float s[16];
#pragma unroll
        for (int i = 0; i < 16; ++i) s[i] = 0.f;

        int colbase = (bid >> 6) * 512 + (wave & 1) * 64;
        int cb4 = colbase >> 4;
        bf16x8 b[4];
#pragma unroll
        for (int kt = 0; kt < 4; ++kt)
            b[kt] = zf[(size_t)(cb4 * 4 + kt) * 64 + lane];

#pragma unroll 1
        for (int it = 0; it < 4; ++it) {
#pragma unroll
            for (int nt = 0; nt < 4; ++nt) {
                // prefetch next B fragment group
                bf16x8 bn[4];
                if (!(it == 3 && nt == 3)) {
                    int ng = cb4 + (nt == 3 ? (it + 1) * 8 : it * 8 + nt + 1);
#pragma unroll
                    for (int kt = 0; kt < 4; ++kt)
                        bn[kt] = zf[(size_t)(ng * 4 + kt) * 64 + lane];
                }
                f32x4 acc[4];
                f32x4 zero = {0.f, 0.f, 0.f, 0.f};
#pragma unroll
                for (int mt = 0; mt < 4; ++mt) acc[mt] = zero;
#pragma unroll
                for (int kt = 0; kt < 4; ++kt)
#pragma unroll
                    for (int mt = 0; mt < 4; ++mt)
                        acc[mt] = __builtin_amdgcn_mfma_f32_16x16x32_bf16(a[mt][kt], b[kt], acc[mt], 0, 0, 0);
                int gcol = colbase + it * 128 + nt * 16 + t;
#pragma unroll
                for (int mt = 0; mt < 4; ++mt) {
                    int rowb = row0 + mt * 16 + q * 4;
#pragma unroll
                    for (int reg = 0; reg < 4; ++reg) {
                        float e = __expf(acc[mt][reg]);
                        s[mt * 4 + reg] += (rowb + reg == gcol) ? 0.f : e;
                    }
                }
#pragma unroll
                for (int kt = 0; kt < 4; ++kt) b[kt] = bn[kt];
            }
        }
#pragma unroll
        for (int i = 0; i < 16; ++i) {
            float v = s[i];
            v += __shfl_xor(v, 1, 64);
            v += __shfl_xor(v, 2, 64);
            v += __shfl_xor(v, 4, 64);
            v += __shfl_xor(v, 8, 64);
            if (t == 0) atomicAdd(&S_row[row0 + (i >> 2) * 16 + q * 4 + (i & 3)], v);
        }
    } else {
        int r = (bid - 1024) * 4 + wave;
        const float* h = (r < BATCH) ? (h_i + (size_t)r * LATENT)
                                     : (h_j + (size_t)(r - BATCH) * LATENT);
        const float4* h4 = (const float4*)h;
        const float4* w4 = (const float4*)W;
        float s = 0.f;
#pragma unroll
        for (int itr = 0; itr < 8; ++itr) {
            float4 av = h4[itr * 64 + lane];
            float4 wv = w4[itr * 64 + lane];
            s += av.x * wv.x + av.y * wv.y + av.z * wv.z + av.w * wv.w;
        }
        s = wave_reduce_sum(s);
        if (lane == 0) logits[r] = s + bb[0];
    }
}

// Single block: nnPU risk from logits+target, NT-Xent sum from S_row+pos,
// weighted combine.
__global__ void k_final(const float* __restrict__ S_row, const float* __restrict__ pos,
                        const float* __restrict__ logits, const int* __restrict__ target,
                        const float* __restrict__ w_onnpu, float* __restrict__ out) {
    float nt_s = 0.f;
    for (int r = threadIdx.x; r < NROWS; r += 1024)
        nt_s += __logf(S_row[r]) - pos[r];
    float v[8];
#pragma unroll
    for (int i = 0; i < 8; ++i) v[i] = 0.f;
    for (int r = threadIdx.x; r < BATCH; r += 1024) {
        float li = logits[r], lj = logits[BATCH + r];
        bool p = (target[r] == 1);
        float si_n = 1.f / (1.f + __expf(li));
        float si_p = 1.f / (1.f + __expf(-li));
        float sj_n = 1.f / (1.f + __expf(lj));
        float sj_p = 1.f / (1.f + __expf(-lj));
        v[0] += p ? 1.f : 0.f;
        v[1] += p ? 0.f : 1.f;
        v[2] += p ? si_n : 0.f;
        v[3] += p ? si_p : 0.f;
        v[4] += p ? 0.f : si_p;
        v[5] += p ? sj_n : 0.f;
        v[6] += p ? sj_p : 0.f;
        v[7] += p ? 0.f : sj_p;
    }
    __shared__ float red[16][9];
    int wave = threadIdx.x >> 6, lane = threadIdx.x & 63;
    nt_s = wave_reduce_sum(nt_s);
#pragma unroll
    for (int i = 0; i < 8; ++i) v[i] = wave_reduce_sum(v[i]);
    if (lane == 0) {
        red[wave][0] = nt_s;
#pragma unroll
        for (int i = 0; i < 8; ++i) red[wave][1 + i] = v[i];
    }
    __syncthreads();
    if (threadIdx.x == 0) {
        float t[9];
#pragma unroll
        for (int i = 0; i < 9; ++i) {
            float acc = 0.f;
#pragma unroll
            for (int wv = 0; wv < 16; ++wv) acc += red[wv][i];
            t[i] = acc;
        }
        float ntxent = t[0] / (float)NROWS;
        float np = fmaxf(1.f, t[1]), nu = fmaxf(1.f, t[2]);
        float pr_i = PRIOR_PRIMEc / np * t[3];
        float nr_i = (1.f - PRIOR_PRIMEc) / (nu * (1.f - PRIORc)) * t[5]
                   - (1.f - PRIOR_PRIMEc) * PRIORc / (np * (1.f - PRIORc)) * t[4];
        float li_loss = (nr_i < 0.f) ? -nr_i : (pr_i + nr_i);
        float pr_j = PRIOR_PRIMEc / np * t[6];
        float nr_j = (1.f - PRIOR_PRIMEc) / (nu * (1.f - PRIORc)) * t[8]
                   - (1.f - PRIOR_PRIMEc) * PRIORc / (np * (1.f - PRIORc)) * t[7];
        float lj_loss = (nr_j < 0.f) ? -nr_j : (pr_j + nr_j);
        float onnpu = 0.5f * (li_loss + lj_loss);
        float w = w_onnpu[0];
        out[0] = w * onnpu + (1.f - w) * ntxent;
    }
}

extern "C" void kernel_launch(void* const* d_in, const int* in_sizes, int n_in,
                              void* d_out, int out_size, void* d_ws, size_t ws_size,
                              hipStream_t stream) {
    const float* h_i = (const float*)d_in[0];
    const float* h_j = (const float*)d_in[1];
    const float* z_i = (const float*)d_in[2];
    const float* z_j = (const float*)d_in[3];
    const int* target = (const int*)d_in[4];
    const float* W = (const float*)d_in[5];
    const float* b = (const float*)d_in[6];
    const float* w_onnpu = (const float*)d_in[7];

    char* ws = (char*)d_ws;
    unsigned short* znb = (unsigned short*)ws;              // 2 MB swizzled bf16
    float* S_row  = (float*)(ws + 2097152);                 // 32 KB
    float* pos    = (float*)(ws + 2097152 + 32768);         // 32 KB
    float* logits = (float*)(ws + 2097152 + 65536);         // 32 KB
    float* out = (float*)d_out;

    hipMemsetAsync(S_row, 0, 32768, stream);
    k_zprep<<<1024, 256, 0, stream>>>(z_i, z_j, znb, pos);
    k_mega<<<3072, 256, 0, stream>>>(znb, S_row, h_i, h_j, W, b, logits);
    k_final<<<1, 1024, 0, stream>>>(S_row, pos, logits, target, w_onnpu, out);
}